// Round 4
// baseline (288.201 us; speedup 1.0000x reference)
//
#include <hip/hip_runtime.h>
#include <hip/hip_bf16.h>
#include <stdint.h>

#define ALPHA_ 0.2f
#define EPS_   1e-6f

typedef __attribute__((ext_vector_type(8))) short  short8;
typedef __attribute__((ext_vector_type(4))) float  float4v;

static __device__ __forceinline__ unsigned short f2bf(float x) {
    union { float f; unsigned int u; } c; c.f = x;
    return (unsigned short)((c.u + 0x7fffu + ((c.u >> 16) & 1u)) >> 16);
}

// ---------------- K0: WT in MFMA-B-fragment order (for k_wh) ----------------
__global__ __launch_bounds__(256) void k_wt(const float* __restrict__ W,
                                            unsigned short* __restrict__ WTs) {
    const int g  = blockIdx.x * 256 + threadIdx.x;   // 8192 threads
    const int fb = g >> 9, kc = (g >> 6) & 7, l = g & 63;
    const int m = l & 15, quad = l >> 4;
    const int f = fb * 16 + m, d0 = kc * 32 + quad * 8;
    unsigned short v[8];
#pragma unroll
    for (int i = 0; i < 8; ++i) v[i] = f2bf(W[(d0 + i) * 256 + f]);
    uint4 o;
    o.x = (unsigned)v[0] | ((unsigned)v[1] << 16);
    o.y = (unsigned)v[2] | ((unsigned)v[3] << 16);
    o.z = (unsigned)v[4] | ((unsigned)v[5] << 16);
    o.w = (unsigned)v[6] | ((unsigned)v[7] << 16);
    *(uint4*)(WTs + (size_t)g * 8) = o;
}

// ---------------- K1: MFMA Wh = h@W; fused s1/s2; WhS in B-frag order -------
__global__ __launch_bounds__(512) void k_wh(const float* __restrict__ h,
                                            const unsigned short* __restrict__ WTs,
                                            const float* __restrict__ a,
                                            unsigned short* __restrict__ WhS,
                                            float* __restrict__ s1g,
                                            float* __restrict__ s2g) {
    __shared__ __align__(16) unsigned short A_lds[32][264];   // pad 256->264
    __shared__ __align__(16) unsigned short T_lds[256][40];   // [f][j] pad 32->40
    __shared__ float s1p[32], s2p[32];
    const int t    = threadIdx.x;
    const int lane = t & 63;
    const int wv   = t >> 6;              // 0..7
    const int m    = lane & 15;
    const int quad = lane >> 4;
    const int r0   = blockIdx.x * 32;     // 512 blocks
    const int b    = blockIdx.x >> 6;
    const int jc   = blockIdx.x & 63;
    const int j0   = r0 & 2047;

    if (t < 32) { s1p[t] = 0.f; s2p[t] = 0.f; }

    // stage h tile fp32 -> bf16 LDS (coalesced float4)
#pragma unroll
    for (int k = 0; k < 4; ++k) {
        const int flat = t + k * 512;
        const int r  = flat >> 6;
        const int d4 = flat & 63;
        float4v hv = *(const float4v*)(h + (size_t)(r0 + r) * 256 + d4 * 4);
        uint2 pk;
        pk.x = (unsigned)f2bf(hv.x) | ((unsigned)f2bf(hv.y) << 16);
        pk.y = (unsigned)f2bf(hv.z) | ((unsigned)f2bf(hv.w) << 16);
        *(uint2*)&A_lds[r][d4 * 4] = pk;
    }
    __syncthreads();

    const int fbase = wv * 32;
    float4v acc[2][2];
#pragma unroll
    for (int it = 0; it < 2; ++it)
#pragma unroll
        for (int ft = 0; ft < 2; ++ft)
#pragma unroll
            for (int r = 0; r < 4; ++r) acc[it][ft][r] = 0.f;

    const unsigned short* wtb = WTs + (size_t)(wv * 2) * 4096 + lane * 8;

#pragma unroll
    for (int kc = 0; kc < 8; ++kc) {
        short8 af0 = *(const short8*)&A_lds[m][kc * 32 + quad * 8];
        short8 af1 = *(const short8*)&A_lds[16 + m][kc * 32 + quad * 8];
#pragma unroll
        for (int ft = 0; ft < 2; ++ft) {
            short8 bf = *(const short8*)(wtb + (size_t)ft * 4096 + kc * 512);
            acc[0][ft] = __builtin_amdgcn_mfma_f32_16x16x32_bf16(af0, bf, acc[0][ft], 0, 0, 0);
            acc[1][ft] = __builtin_amdgcn_mfma_f32_16x16x32_bf16(af1, bf, acc[1][ft], 0, 0, 0);
        }
    }

    // fused s1/s2
    float a1v[2], a2v[2];
#pragma unroll
    for (int ft = 0; ft < 2; ++ft) {
        a1v[ft] = a[fbase + ft * 16 + m];
        a2v[ft] = a[256 + fbase + ft * 16 + m];
    }
#pragma unroll
    for (int it = 0; it < 2; ++it) {
#pragma unroll
        for (int reg = 0; reg < 4; ++reg) {
            float v1 = 0.f, v2 = 0.f;
#pragma unroll
            for (int ft = 0; ft < 2; ++ft) {
                const float c = acc[it][ft][reg];
                v1 = fmaf(c, a1v[ft], v1);
                v2 = fmaf(c, a2v[ft], v2);
            }
            v1 += __shfl_xor(v1, 1); v2 += __shfl_xor(v2, 1);
            v1 += __shfl_xor(v1, 2); v2 += __shfl_xor(v2, 2);
            v1 += __shfl_xor(v1, 4); v2 += __shfl_xor(v2, 4);
            v1 += __shfl_xor(v1, 8); v2 += __shfl_xor(v2, 8);
            if (m == 0) {
                const int row = it * 16 + quad * 4 + reg;
                atomicAdd(&s1p[row], v1);
                atomicAdd(&s2p[row], v2);
            }
        }
    }

    // C -> T_lds[f][j]
#pragma unroll
    for (int it = 0; it < 2; ++it)
#pragma unroll
        for (int ft = 0; ft < 2; ++ft)
#pragma unroll
            for (int reg = 0; reg < 4; ++reg)
                T_lds[fbase + ft * 16 + m][it * 16 + quad * 4 + reg] =
                    f2bf(acc[it][ft][reg]);

    __syncthreads();   // cross-wave T_lds reads below

    // swizzled store: WhS[(b*64+jc)*16 + fb][l] = T_lds[fb*16 + (l&15)][(l>>4)*8 ..+8]
#pragma unroll
    for (int e = 0; e < 2; ++e) {
        const int idx = e * 512 + t;
        const int fb = idx >> 6, l = idx & 63;
        uint4 v = *(const uint4*)&T_lds[fb * 16 + (l & 15)][(l >> 4) * 8];
        *(uint4*)(WhS + ((size_t)(b * 64 + jc) * 16 + fb) * 512 + l * 8) = v;
    }

    if (t < 32) {
        s1g[(size_t)b * 2048 + j0 + t] = s1p[t];
        s2g[(size_t)b * 2048 + j0 + t] = s2p[t];
    }
}

// ---------------- K3: fragment-direct, barrier-free j-sweep ----------------
// R4 structure: each wave independently owns i16 x f64 and sweeps all 2048 j.
// P is computed DIRECTLY in A-fragment register layout (lane l = row l&15,
// k-slot (l>>4)*8+e), so the per-step LDS round-trip (ds_write -> barrier ->
// ds_read) and ALL in-loop barriers are gone. Waves desync naturally; memory
// latency overlaps across the 16 waves/CU without lockstep stalls.
// s2 staged once in LDS (broadcast reads, conflict-free); s1 one scalar/lane.
// Grid: itile(32) x fq(4) x b(8) = 1024 blocks; blk&7=b pins batch->XCD so
// adj stream + WhS slice (1MB) stay in that XCD's L2.
static __device__ __forceinline__ unsigned pk2bf(float lo, float hi) {
    float2 v; v.x = lo; v.y = hi;
    union { __hip_bfloat162 h2; unsigned u; } cv;
    cv.h2 = __float22bfloat162_rn(v);
    return cv.u;
}

static __device__ __forceinline__ uint2 pquad(float4v av, float4v s2v,
                                              float s1, float& rs) {
    float e0 = s1 + s2v.x, e1 = s1 + s2v.y, e2 = s1 + s2v.z, e3 = s1 + s2v.w;
    e0 = fmaxf(e0, ALPHA_ * e0); e1 = fmaxf(e1, ALPHA_ * e1);
    e2 = fmaxf(e2, ALPHA_ * e2); e3 = fmaxf(e3, ALPHA_ * e3);
    const float p0 = (av.x + EPS_) * __expf(e0);
    const float p1 = (av.y + EPS_) * __expf(e1);
    const float p2 = (av.z + EPS_) * __expf(e2);
    const float p3 = (av.w + EPS_) * __expf(e3);
    rs += (p0 + p1) + (p2 + p3);
    uint2 r;
    r.x = pk2bf(p0, p1);
    r.y = pk2bf(p2, p3);
    return r;
}

__global__ __launch_bounds__(256, 4) void k_attn(const float* __restrict__ adj,
                                                 const unsigned short* __restrict__ WhS,
                                                 const float* __restrict__ s1g,
                                                 const float* __restrict__ s2g,
                                                 float* __restrict__ out) {
    __shared__ __align__(16) float s2_lds[2048];   // 8KB, whole s2 row of b

    const int t    = threadIdx.x;
    const int lane = t & 63;
    const int w    = t >> 6;             // wave 0..3 -> i-subtile
    const int m    = lane & 15;
    const int quad = lane >> 4;
    const int blk  = blockIdx.x;
    const int b     = blk & 7;           // XCD-pinned batch
    const int fq    = (blk >> 3) & 3;    // f quarter (64 cols)
    const int itile = blk >> 5;          // 0..31 (64 rows each)

    const int irow = itile * 64 + w * 16 + m;     // this lane's adj/P row

    // stage s2 once (no in-loop barriers after this)
    {
        const float* s2src = s2g + (size_t)b * 2048;
        *(float4v*)&s2_lds[t * 8]     = *(const float4v*)(s2src + t * 8);
        *(float4v*)&s2_lds[t * 8 + 4] = *(const float4v*)(s2src + t * 8 + 4);
    }

    const float  s1v  = s1g[(size_t)b * 2048 + irow];
    const float* adjR = adj + (size_t)(b * 2048 + irow) * 2048 + quad * 8;
    const unsigned short* whs =
        WhS + (size_t)b * 64 * 16 * 512 + (size_t)(fq * 4) * 512 + lane * 8;

    float4v acc[4];
#pragma unroll
    for (int ft = 0; ft < 4; ++ft)
#pragma unroll
        for (int r = 0; r < 4; ++r) acc[ft][r] = 0.f;

    float rs = 0.f;

    // prologue: step-0 adj in registers (8 x float4, single-buffered WAR reuse)
    float4v adjv[8];
#pragma unroll
    for (int kc = 0; kc < 4; ++kc) {
        adjv[kc * 2]     = *(const float4v*)(adjR + kc * 32);
        adjv[kc * 2 + 1] = *(const float4v*)(adjR + kc * 32 + 4);
    }

    __syncthreads();   // one-time: s2_lds visible

    for (int step = 0; step < 16; ++step) {
        // ---- p-compute directly into A-fragment layout ----
        short8 pa[4];
#pragma unroll
        for (int kc = 0; kc < 4; ++kc) {
            const int jb = step * 128 + kc * 32 + quad * 8;
            float4v s2a = *(const float4v*)&s2_lds[jb];
            float4v s2b = *(const float4v*)&s2_lds[jb + 4];
            uint2 lo = pquad(adjv[kc * 2],     s2a, s1v, rs);
            uint2 hi = pquad(adjv[kc * 2 + 1], s2b, s1v, rs);
            union { uint4 u; short8 s; } P;
            P.u.x = lo.x; P.u.y = lo.y; P.u.z = hi.x; P.u.w = hi.y;
            pa[kc] = P.s;
        }

        // ---- prefetch next step's adj (no barrier -> latency hides under MFMA) ----
        const int ns = (step + 1) & 15;   // wrap: harmless reload
#pragma unroll
        for (int kc = 0; kc < 4; ++kc) {
            adjv[kc * 2]     = *(const float4v*)(adjR + (size_t)ns * 128 + kc * 32);
            adjv[kc * 2 + 1] = *(const float4v*)(adjR + (size_t)ns * 128 + kc * 32 + 4);
        }

        // ---- MFMA: B-frags lane-contiguous 1KB L2 reads, A in registers ----
#pragma unroll
        for (int kc = 0; kc < 4; ++kc) {
            const unsigned short* bp = whs + (size_t)((step * 4 + kc) * 16) * 512;
#pragma unroll
            for (int ft = 0; ft < 4; ++ft) {
                short8 bf = *(const short8*)(bp + (size_t)ft * 512);
                acc[ft] = __builtin_amdgcn_mfma_f32_16x16x32_bf16(pa[kc], bf, acc[ft], 0, 0, 0);
            }
        }
    }

    // rowsum: rs covers row m's j-slots of this quad; reduce across quads
    rs += __shfl_xor(rs, 16);
    rs += __shfl_xor(rs, 32);
    // lanes 0..15 now hold full rowsums for rows 0..15 (replicated per quad)

    // epilogue: C/D col = m (f), row = quad*4+reg (i)
#pragma unroll
    for (int reg = 0; reg < 4; ++reg) {
        const float rsum = __shfl(rs, quad * 4 + reg);
        const float inv  = 1.0f / rsum;
        const int orow = itile * 64 + w * 16 + quad * 4 + reg;
#pragma unroll
        for (int ft = 0; ft < 4; ++ft) {
            const int f = fq * 64 + ft * 16 + m;
            out[(size_t)(b * 2048 + orow) * 256 + f] = acc[ft][reg] * inv;
        }
    }
}

extern "C" void kernel_launch(void* const* d_in, const int* in_sizes, int n_in,
                              void* d_out, int out_size, void* d_ws, size_t ws_size,
                              hipStream_t stream) {
    const float* h   = (const float*)d_in[0];   // (8,2048,256)
    const float* adj = (const float*)d_in[1];   // (8,2048,2048)
    const float* W   = (const float*)d_in[2];   // (256,256)
    const float* a   = (const float*)d_in[3];   // (512,1)
    float* out = (float*)d_out;                 // (8,2048,256)

    unsigned short* WhS = (unsigned short*)d_ws;                        // 8.4 MB
    unsigned short* WTs = (unsigned short*)((char*)d_ws + 8388608);     // 128 KB
    float*          s1  = (float*)((char*)d_ws + 8388608 + 131072);     // 64 KB
    float*          s2  = s1 + 16384;                                   // 64 KB

    k_wt  <<<dim3(32),   dim3(256), 0, stream>>>(W, WTs);
    k_wh  <<<dim3(512),  dim3(512), 0, stream>>>(h, WTs, a, WhS, s1, s2);
    k_attn<<<dim3(1024), dim3(256), 0, stream>>>(adj, WhS, s1, s2, out);
}

// Round 5
// 235.460 us; speedup vs baseline: 1.2240x; 1.2240x over previous
//
#include <hip/hip_runtime.h>
#include <hip/hip_bf16.h>
#include <stdint.h>

#define ALPHA_ 0.2f
#define EPS_   1e-6f

typedef __attribute__((ext_vector_type(8))) short  short8;
typedef __attribute__((ext_vector_type(4))) float  float4v;

static __device__ __forceinline__ unsigned short f2bf(float x) {
    union { float f; unsigned int u; } c; c.f = x;
    return (unsigned short)((c.u + 0x7fffu + ((c.u >> 16) & 1u)) >> 16);
}

// ---------------- K0: WT in MFMA-B-fragment order (for k_wh) ----------------
__global__ __launch_bounds__(256) void k_wt(const float* __restrict__ W,
                                            unsigned short* __restrict__ WTs) {
    const int g  = blockIdx.x * 256 + threadIdx.x;   // 8192 threads
    const int fb = g >> 9, kc = (g >> 6) & 7, l = g & 63;
    const int m = l & 15, quad = l >> 4;
    const int f = fb * 16 + m, d0 = kc * 32 + quad * 8;
    unsigned short v[8];
#pragma unroll
    for (int i = 0; i < 8; ++i) v[i] = f2bf(W[(d0 + i) * 256 + f]);
    uint4 o;
    o.x = (unsigned)v[0] | ((unsigned)v[1] << 16);
    o.y = (unsigned)v[2] | ((unsigned)v[3] << 16);
    o.z = (unsigned)v[4] | ((unsigned)v[5] << 16);
    o.w = (unsigned)v[6] | ((unsigned)v[7] << 16);
    *(uint4*)(WTs + (size_t)g * 8) = o;
}

// ---------------- K1: MFMA Wh = h@W; fused s1/s2; WhS in B-frag order -------
__global__ __launch_bounds__(512) void k_wh(const float* __restrict__ h,
                                            const unsigned short* __restrict__ WTs,
                                            const float* __restrict__ a,
                                            unsigned short* __restrict__ WhS,
                                            float* __restrict__ s1g,
                                            float* __restrict__ s2g) {
    __shared__ __align__(16) unsigned short A_lds[32][264];   // pad 256->264
    __shared__ __align__(16) unsigned short T_lds[256][40];   // [f][j] pad 32->40
    __shared__ float s1p[32], s2p[32];
    const int t    = threadIdx.x;
    const int lane = t & 63;
    const int wv   = t >> 6;              // 0..7
    const int m    = lane & 15;
    const int quad = lane >> 4;
    const int r0   = blockIdx.x * 32;     // 512 blocks
    const int b    = blockIdx.x >> 6;
    const int jc   = blockIdx.x & 63;
    const int j0   = r0 & 2047;

    if (t < 32) { s1p[t] = 0.f; s2p[t] = 0.f; }

    // stage h tile fp32 -> bf16 LDS (coalesced float4)
#pragma unroll
    for (int k = 0; k < 4; ++k) {
        const int flat = t + k * 512;
        const int r  = flat >> 6;
        const int d4 = flat & 63;
        float4v hv = *(const float4v*)(h + (size_t)(r0 + r) * 256 + d4 * 4);
        uint2 pk;
        pk.x = (unsigned)f2bf(hv.x) | ((unsigned)f2bf(hv.y) << 16);
        pk.y = (unsigned)f2bf(hv.z) | ((unsigned)f2bf(hv.w) << 16);
        *(uint2*)&A_lds[r][d4 * 4] = pk;
    }
    __syncthreads();

    const int fbase = wv * 32;
    float4v acc[2][2];
#pragma unroll
    for (int it = 0; it < 2; ++it)
#pragma unroll
        for (int ft = 0; ft < 2; ++ft)
#pragma unroll
            for (int r = 0; r < 4; ++r) acc[it][ft][r] = 0.f;

    const unsigned short* wtb = WTs + (size_t)(wv * 2) * 4096 + lane * 8;

#pragma unroll
    for (int kc = 0; kc < 8; ++kc) {
        short8 af0 = *(const short8*)&A_lds[m][kc * 32 + quad * 8];
        short8 af1 = *(const short8*)&A_lds[16 + m][kc * 32 + quad * 8];
#pragma unroll
        for (int ft = 0; ft < 2; ++ft) {
            short8 bf = *(const short8*)(wtb + (size_t)ft * 4096 + kc * 512);
            acc[0][ft] = __builtin_amdgcn_mfma_f32_16x16x32_bf16(af0, bf, acc[0][ft], 0, 0, 0);
            acc[1][ft] = __builtin_amdgcn_mfma_f32_16x16x32_bf16(af1, bf, acc[1][ft], 0, 0, 0);
        }
    }

    // fused s1/s2
    float a1v[2], a2v[2];
#pragma unroll
    for (int ft = 0; ft < 2; ++ft) {
        a1v[ft] = a[fbase + ft * 16 + m];
        a2v[ft] = a[256 + fbase + ft * 16 + m];
    }
#pragma unroll
    for (int it = 0; it < 2; ++it) {
#pragma unroll
        for (int reg = 0; reg < 4; ++reg) {
            float v1 = 0.f, v2 = 0.f;
#pragma unroll
            for (int ft = 0; ft < 2; ++ft) {
                const float c = acc[it][ft][reg];
                v1 = fmaf(c, a1v[ft], v1);
                v2 = fmaf(c, a2v[ft], v2);
            }
            v1 += __shfl_xor(v1, 1); v2 += __shfl_xor(v2, 1);
            v1 += __shfl_xor(v1, 2); v2 += __shfl_xor(v2, 2);
            v1 += __shfl_xor(v1, 4); v2 += __shfl_xor(v2, 4);
            v1 += __shfl_xor(v1, 8); v2 += __shfl_xor(v2, 8);
            if (m == 0) {
                const int row = it * 16 + quad * 4 + reg;
                atomicAdd(&s1p[row], v1);
                atomicAdd(&s2p[row], v2);
            }
        }
    }

    // C -> T_lds[f][j]
#pragma unroll
    for (int it = 0; it < 2; ++it)
#pragma unroll
        for (int ft = 0; ft < 2; ++ft)
#pragma unroll
            for (int reg = 0; reg < 4; ++reg)
                T_lds[fbase + ft * 16 + m][it * 16 + quad * 4 + reg] =
                    f2bf(acc[it][ft][reg]);

    __syncthreads();   // cross-wave T_lds reads below

    // swizzled store: WhS[(b*64+jc)*16 + fb][l] = T_lds[fb*16 + (l&15)][(l>>4)*8 ..+8]
#pragma unroll
    for (int e = 0; e < 2; ++e) {
        const int idx = e * 512 + t;
        const int fb = idx >> 6, l = idx & 63;
        uint4 v = *(const uint4*)&T_lds[fb * 16 + (l & 15)][(l >> 4) * 8];
        *(uint4*)(WhS + ((size_t)(b * 64 + jc) * 16 + fb) * 512 + l * 8) = v;
    }

    if (t < 32) {
        s1g[(size_t)b * 2048 + j0 + t] = s1p[t];
        s2g[(size_t)b * 2048 + j0 + t] = s2p[t];
    }
}

// ---------------- K3: R0 structure, fh-merged (ONE change vs R0) ------------
// Evidence: R0 (78us) beat all structural rewrites (R1 86, R3 110, R4 131).
// R0's remaining redundancy: the fh in {0,1} split made each (b,itile) pair
// compute the full 32x2048 P tile TWICE and read adj twice. This version
// merges the halves: 512-thread / 8-wave blocks, each wave owns f32
// (fbb = wv*2, covers all 256 f). Per-wave MFMA pattern, pbuf dbuf,
// one-barrier-per-step, adj/s2 register prefetch: identical to R0.
// Occupancy unchanged (1024 thr/CU = 4 waves/SIMD). Total exp count and adj
// traffic HALVE; B-fragment L2 traffic unchanged.
static __device__ __forceinline__ unsigned pk2bf(float lo, float hi) {
    float2 v; v.x = lo; v.y = hi;
    union { __hip_bfloat162 h2; unsigned u; } cv;
    cv.h2 = __float22bfloat162_rn(v);
    return cv.u;
}

static __device__ __forceinline__ uint2 pquad(float4v av, float4v s2v,
                                              float s1, float& rs) {
    float e0 = s1 + s2v.x, e1 = s1 + s2v.y, e2 = s1 + s2v.z, e3 = s1 + s2v.w;
    e0 = fmaxf(e0, ALPHA_ * e0); e1 = fmaxf(e1, ALPHA_ * e1);
    e2 = fmaxf(e2, ALPHA_ * e2); e3 = fmaxf(e3, ALPHA_ * e3);
    const float p0 = (av.x + EPS_) * __expf(e0);
    const float p1 = (av.y + EPS_) * __expf(e1);
    const float p2 = (av.z + EPS_) * __expf(e2);
    const float p3 = (av.w + EPS_) * __expf(e3);
    rs += (p0 + p1) + (p2 + p3);
    uint2 r;
    r.x = pk2bf(p0, p1);
    r.y = pk2bf(p2, p3);
    return r;
}

__global__ __launch_bounds__(512, 4) void k_attn(const float* __restrict__ adj,
                                                 const unsigned short* __restrict__ WhS,
                                                 const float* __restrict__ s1g,
                                                 const float* __restrict__ s2g,
                                                 float* __restrict__ out) {
    __shared__ __align__(16) unsigned short pbuf[2][32][140];  // pad 128->140
    __shared__ float rsum_lds[32];

    const int t    = threadIdx.x;
    const int lane = t & 63;
    const int wv   = t >> 6;             // 0..7
    const int m    = lane & 15;
    const int quad = lane >> 4;
    const int blk  = blockIdx.x;
    const int b    = blk & 7;            // XCD-pinned batch
    const int i0   = (blk >> 3) * 32;    // 64 i-tiles of 32 rows

    const int ip = t >> 4;               // 0..31  (i-row)
    const int jq = t & 15;               // 0..15  (j-octet)

    const float* adjp = adj + (size_t)(b * 2048 + i0 + ip) * 2048 + jq * 8;
    const float* s2p  = s2g + (size_t)b * 2048 + jq * 8;
    const float  s1v  = s1g[(size_t)b * 2048 + i0 + ip];

    const int fbb = wv * 2;              // this wave's first f-block (of 16)
    const unsigned short* whs = WhS + (size_t)b * 64 * 16 * 512;

    float4v acc[2][2];   // [it][ft]
#pragma unroll
    for (int it = 0; it < 2; ++it)
#pragma unroll
        for (int ft = 0; ft < 2; ++ft)
#pragma unroll
            for (int r = 0; r < 4; ++r) acc[it][ft][r] = 0.f;

    float rs = 0.f;

    // prologue: step-0 adj/s2 in registers (coalesced 8-float-per-thread rows)
    float4v adjv[2], s2v[2];
#pragma unroll
    for (int c = 0; c < 2; ++c) {
        adjv[c] = *(const float4v*)(adjp + c * 4);
        s2v[c]  = *(const float4v*)(s2p + c * 4);
    }

    for (int step = 0; step < 16; ++step) {
        const int cur = step & 1;

        // ---- p (fp32) -> bf16, ds_write into pbuf[cur] ----
#pragma unroll
        for (int c = 0; c < 2; ++c) {
            uint2 pk = pquad(adjv[c], s2v[c], s1v, rs);
            *(uint2*)&pbuf[cur][ip][jq * 8 + c * 4] = pk;
        }

        // register-prefetch next step (stays in flight across barrier)
        const int ns = (step + 1) & 15;  // wrap: harmless reload
#pragma unroll
        for (int c = 0; c < 2; ++c) {
            adjv[c] = *(const float4v*)(adjp + (size_t)ns * 128 + c * 4);
            s2v[c]  = *(const float4v*)(s2p + (size_t)ns * 128 + c * 4);
        }

        __syncthreads();   // pbuf[cur] visible; dbuf -> one barrier per step

        // ---- MFMA: B-frags are lane-contiguous 1KB L2 reads ----
#pragma unroll
        for (int kc = 0; kc < 4; ++kc) {
            const unsigned short* bp =
                whs + ((size_t)((step * 4 + kc) * 16 + fbb)) * 512 + lane * 8;
            short8 bf0 = *(const short8*)bp;
            short8 bf1 = *(const short8*)(bp + 512);
            short8 af0 = *(const short8*)&pbuf[cur][m][kc * 32 + quad * 8];
            short8 af1 = *(const short8*)&pbuf[cur][16 + m][kc * 32 + quad * 8];
            acc[0][0] = __builtin_amdgcn_mfma_f32_16x16x32_bf16(af0, bf0, acc[0][0], 0, 0, 0);
            acc[0][1] = __builtin_amdgcn_mfma_f32_16x16x32_bf16(af0, bf1, acc[0][1], 0, 0, 0);
            acc[1][0] = __builtin_amdgcn_mfma_f32_16x16x32_bf16(af1, bf0, acc[1][0], 0, 0, 0);
            acc[1][1] = __builtin_amdgcn_mfma_f32_16x16x32_bf16(af1, bf1, acc[1][1], 0, 0, 0);
        }
    }

    // rowsum: lanes xor 1,2,4,8 share ip (t = ip*16 + jq)
    rs += __shfl_xor(rs, 1);
    rs += __shfl_xor(rs, 2);
    rs += __shfl_xor(rs, 4);
    rs += __shfl_xor(rs, 8);
    if (jq == 0) rsum_lds[ip] = rs;
    __syncthreads();

    // epilogue: C/D col = lane&15 (f), row = quad*4+reg (i), +16 per it
#pragma unroll
    for (int reg = 0; reg < 4; ++reg) {
        const int row  = quad * 4 + reg;
        const float i0v = 1.0f / rsum_lds[row];
        const float i1v = 1.0f / rsum_lds[16 + row];
#pragma unroll
        for (int ft = 0; ft < 2; ++ft) {
            const int f = wv * 32 + ft * 16 + m;
            out[(size_t)(b * 2048 + i0 + row) * 256 + f]      = acc[0][ft][reg] * i0v;
            out[(size_t)(b * 2048 + i0 + 16 + row) * 256 + f] = acc[1][ft][reg] * i1v;
        }
    }
}

extern "C" void kernel_launch(void* const* d_in, const int* in_sizes, int n_in,
                              void* d_out, int out_size, void* d_ws, size_t ws_size,
                              hipStream_t stream) {
    const float* h   = (const float*)d_in[0];   // (8,2048,256)
    const float* adj = (const float*)d_in[1];   // (8,2048,2048)
    const float* W   = (const float*)d_in[2];   // (256,256)
    const float* a   = (const float*)d_in[3];   // (512,1)
    float* out = (float*)d_out;                 // (8,2048,256)

    unsigned short* WhS = (unsigned short*)d_ws;                        // 8.4 MB
    unsigned short* WTs = (unsigned short*)((char*)d_ws + 8388608);     // 128 KB
    float*          s1  = (float*)((char*)d_ws + 8388608 + 131072);     // 64 KB
    float*          s2  = s1 + 16384;                                   // 64 KB

    k_wt  <<<dim3(32),   dim3(256), 0, stream>>>(W, WTs);
    k_wh  <<<dim3(512),  dim3(512), 0, stream>>>(h, WTs, a, WhS, s1, s2);
    k_attn<<<dim3(512),  dim3(512), 0, stream>>>(adj, WhS, s1, s2, out);
}